// Round 5
// baseline (221.147 us; speedup 1.0000x reference)
//
#include <hip/hip_runtime.h>

#define NB  32
#define NLQ 64
#define NLV 128
#define NQS 512
#define NFS 1024
#define NBN 512

typedef float  floatx4 __attribute__((ext_vector_type(4)));
typedef __bf16 bf16x8  __attribute__((ext_vector_type(8)));

__device__ __forceinline__ unsigned short f2bf(float f) {
    unsigned int u = __float_as_uint(f);
    u += 0x7fffu + ((u >> 16) & 1u);   // round-to-nearest-even
    return (unsigned short)(u >> 16);
}
__device__ __forceinline__ unsigned int pk2(float a, float b) {
    return (unsigned int)f2bf(a) | ((unsigned int)f2bf(b) << 16);
}
__device__ __forceinline__ float blo(unsigned int u) {
    return __uint_as_float(u << 16);
}
__device__ __forceinline__ float bhi(unsigned int u) {
    return __uint_as_float(u & 0xffff0000u);
}

// C[M,N] = A[M,K] @ Bt[N,K]^T (+ bias), A/Bt fp32 in global, bf16 MFMA,
// fp32 accumulate, bf16 output to workspace.  64x64 tile, 4 waves.
__global__ __launch_bounds__(256) void gemm_bt(
    const float* __restrict__ A,
    const float* __restrict__ Bt,
    const float* __restrict__ bias,       // nullptr-like: has_bias==0
    unsigned short* __restrict__ C,
    int M, int N, int K, int has_bias)
{
    __shared__ __align__(16) unsigned short As[64 * 40];  // 32 used + 8 pad
    __shared__ __align__(16) unsigned short Bs[64 * 40];
    const int tid  = threadIdx.x;
    const int m0   = blockIdx.x * 64;
    const int n0   = blockIdx.y * 64;
    const int wave = tid >> 6;
    const int lane = tid & 63;
    const int wm   = (wave >> 1) * 32;
    const int wn   = (wave & 1) * 32;
    const int lrow = tid >> 2;          // 0..63 staging row
    const int lcg  = (tid & 3) * 8;     // k offset (elements) 0,8,16,24
    const int fm   = lane & 15;         // fragment row (m or n)
    const int fk   = (lane >> 4) * 8;   // fragment k base

    floatx4 acc00 = {0,0,0,0}, acc01 = {0,0,0,0};
    floatx4 acc10 = {0,0,0,0}, acc11 = {0,0,0,0};

    const float* ag = A  + (size_t)(m0 + lrow) * K + lcg;
    const float* bg = Bt + (size_t)(n0 + lrow) * K + lcg;

    for (int k0 = 0; k0 < K; k0 += 32) {
        float4 a0 = *(const float4*)(ag + k0);
        float4 a1 = *(const float4*)(ag + k0 + 4);
        float4 b0 = *(const float4*)(bg + k0);
        float4 b1 = *(const float4*)(bg + k0 + 4);
        uint4 av = { pk2(a0.x, a0.y), pk2(a0.z, a0.w), pk2(a1.x, a1.y), pk2(a1.z, a1.w) };
        uint4 bv = { pk2(b0.x, b0.y), pk2(b0.z, b0.w), pk2(b1.x, b1.y), pk2(b1.z, b1.w) };
        __syncthreads();
        *(uint4*)(As + lrow * 40 + lcg) = av;
        *(uint4*)(Bs + lrow * 40 + lcg) = bv;
        __syncthreads();
        bf16x8 fa0 = *(const bf16x8*)(As + (wm + fm) * 40 + fk);
        bf16x8 fa1 = *(const bf16x8*)(As + (wm + 16 + fm) * 40 + fk);
        bf16x8 fb0 = *(const bf16x8*)(Bs + (wn + fm) * 40 + fk);
        bf16x8 fb1 = *(const bf16x8*)(Bs + (wn + 16 + fm) * 40 + fk);
        acc00 = __builtin_amdgcn_mfma_f32_16x16x32_bf16(fa0, fb0, acc00, 0, 0, 0);
        acc01 = __builtin_amdgcn_mfma_f32_16x16x32_bf16(fa0, fb1, acc01, 0, 0, 0);
        acc10 = __builtin_amdgcn_mfma_f32_16x16x32_bf16(fa1, fb0, acc10, 0, 0, 0);
        acc11 = __builtin_amdgcn_mfma_f32_16x16x32_bf16(fa1, fb1, acc11, 0, 0, 0);
    }

    // C/D layout (m89/m91-verified): col = lane&15, row = (lane>>4)*4 + reg
    const int cr = (lane >> 4) * 4;
    const int cc = lane & 15;
    floatx4 accs[2][2] = {{acc00, acc01}, {acc10, acc11}};
    #pragma unroll
    for (int mt = 0; mt < 2; ++mt)
        #pragma unroll
        for (int nt = 0; nt < 2; ++nt)
            #pragma unroll
            for (int r = 0; r < 4; ++r) {
                int gm = m0 + wm + mt * 16 + cr + r;
                int gn = n0 + wn + nt * 16 + cc;
                float v = accs[mt][nt][r];
                if (has_bias) v += bias[gn];
                C[(size_t)gm * N + gn] = f2bf(v);
            }
}

// One block per (b, group of 8 q). 512 threads = 8 waves; wave w owns q = q0+w.
__global__ __launch_bounds__(512) void attend(
    const float*          __restrict__ phr,   // [32,64,512]   fp32
    const float*          __restrict__ vis,   // [32,128,1024] fp32
    const unsigned short* __restrict__ whb,   // [2048,512]    bf16 (Wh + b)
    const unsigned short* __restrict__ uv,    // [4096,512]    bf16 (Uv)
    const float*          __restrict__ wvec,  // [512]         fp32
    float* __restrict__ out_sgf,              // [32,64,1536]  fp32
    float* __restrict__ out_w,                // [32,64,128]   fp32
    float* __restrict__ out_e)                // [32,64,128]   fp32
{
    const float LOG2E = 1.4426950408889634f;
    const float C     = 2.0f * LOG2E;         // exp(2x) = exp2(C*x)
    const int b    = blockIdx.x >> 3;
    const int q0   = (blockIdx.x & 7) << 3;
    const int tid  = threadIdx.x;
    const int wave = tid >> 6;
    const int lane = tid & 63;

    __shared__ float e_s[8][128];
    __shared__ float p_s[8][128];

    // ---------- phase 1: energies e[q, v] ----------
    {
        const int q  = q0 + wave;
        const int n0 = lane << 3;   // this lane's 8 n's
        const unsigned short* wr = whb + (size_t)(b * NLQ + q) * NBN + n0;
        uint4 wv = *(const uint4*)wr;
        float xc[8] = { blo(wv.x) * C, bhi(wv.x) * C, blo(wv.y) * C, bhi(wv.y) * C,
                        blo(wv.z) * C, bhi(wv.z) * C, blo(wv.w) * C, bhi(wv.w) * C };
        float nw2[8];
        float sumw = 0.f;
        #pragma unroll
        for (int j = 0; j < 8; ++j) {
            float w = wvec[n0 + j];
            nw2[j] = 2.f * w;
            sumw += w;
        }
        #pragma unroll
        for (int off = 32; off; off >>= 1) sumw += __shfl_xor(sumw, off);
        // tanh(x) = 1 - 2/(exp(2x)+1)  =>  e_v = sumw - sum_n 2*w_n/(exp2(C*x_n)+1)

        const unsigned short* uvb = uv + (size_t)(b * NLV) * NBN + n0;
        #pragma unroll 2
        for (int v = 0; v < NLV; ++v) {
            uint4 u = *(const uint4*)(uvb + (size_t)v * NBN);
            float s = 0.f;
            auto term = [&](unsigned int uu, int j) {
                float y0 = __builtin_amdgcn_exp2f(fmaf(blo(uu), C, xc[j]));
                float y1 = __builtin_amdgcn_exp2f(fmaf(bhi(uu), C, xc[j + 1]));
                s = fmaf(nw2[j],     __builtin_amdgcn_rcpf(y0 + 1.f), s);
                s = fmaf(nw2[j + 1], __builtin_amdgcn_rcpf(y1 + 1.f), s);
            };
            term(u.x, 0); term(u.y, 2); term(u.z, 4); term(u.w, 6);
            #pragma unroll
            for (int off = 32; off; off >>= 1) s += __shfl_xor(s, off);
            if (lane == 0) e_s[wave][v] = sumw - s;
        }
    }
    __syncthreads();

    // ---------- phase 2: softmax over v (wave handles its q) ----------
    {
        float e0 = e_s[wave][lane];
        float e1 = e_s[wave][lane + 64];
        float m = fmaxf(e0, e1);
        #pragma unroll
        for (int off = 32; off; off >>= 1) m = fmaxf(m, __shfl_xor(m, off));
        float x0 = __builtin_amdgcn_exp2f((e0 - m) * LOG2E);
        float x1 = __builtin_amdgcn_exp2f((e1 - m) * LOG2E);
        float ss = x0 + x1;
        #pragma unroll
        for (int off = 32; off; off >>= 1) ss += __shfl_xor(ss, off);
        float inv = __builtin_amdgcn_rcpf(ss);
        float p0 = x0 * inv, p1 = x1 * inv;
        p_s[wave][lane]      = p0;
        p_s[wave][lane + 64] = p1;
        size_t row = (size_t)(b * NLQ + q0 + wave) * NLV;
        out_w[row + lane]      = p0;
        out_w[row + lane + 64] = p1;
        out_e[row + lane]      = e0;
        out_e[row + lane + 64] = e1;
    }
    __syncthreads();

    // ---------- phase 3: aligned + concat (fp32 out) ----------
    {
        float a0[8], a1[8];
        #pragma unroll
        for (int qq = 0; qq < 8; ++qq) { a0[qq] = 0.f; a1[qq] = 0.f; }
        const float* vrow = vis + (size_t)b * NLV * NFS + 2 * tid;
        #pragma unroll 4
        for (int v = 0; v < NLV; ++v) {
            float2 uu = *(const float2*)(vrow + (size_t)v * NFS);
            #pragma unroll
            for (int qq = 0; qq < 8; ++qq) {
                float pv = p_s[qq][v];           // LDS broadcast
                a0[qq] = fmaf(pv, uu.x, a0[qq]);
                a1[qq] = fmaf(pv, uu.y, a1[qq]);
            }
        }
        const int f0i = 2 * tid;
        #pragma unroll
        for (int qq = 0; qq < 8; ++qq) {
            size_t row = (size_t)(b * NLQ + q0 + qq) * (NQS + NFS);
            float2 o = { a0[qq], a1[qq] };
            *(float2*)(out_sgf + row + NQS + f0i) = o;
        }
        // concat: copy phr rows (fp32 -> fp32) into sgf[:, :512]
        const int qq  = tid >> 6;            // 0..7
        const int col = (tid & 63) << 3;     // 0..504 step 8
        size_t prow = (size_t)(b * NLQ + q0 + qq);
        const float* pr = phr + prow * NQS + col;
        float4 p0v = *(const float4*)pr;
        float4 p1v = *(const float4*)(pr + 4);
        float* dst = out_sgf + prow * (NQS + NFS) + col;
        *(float4*)dst       = p0v;
        *(float4*)(dst + 4) = p1v;
    }
}

extern "C" void kernel_launch(void* const* d_in, const int* in_sizes, int n_in,
                              void* d_out, int out_size, void* d_ws, size_t ws_size,
                              hipStream_t stream) {
    const float* phr  = (const float*)d_in[0];
    const float* vis  = (const float*)d_in[1];
    const float* W    = (const float*)d_in[2];
    const float* U    = (const float*)d_in[3];
    const float* bias = (const float*)d_in[4];
    const float* wvec = (const float*)d_in[5];

    unsigned short* whb = (unsigned short*)d_ws;            // 2048x512 bf16 = 2 MB
    unsigned short* uvb = whb + (size_t)NB * NLQ * NBN;     // 4096x512 bf16 = 4 MB

    float* out     = (float*)d_out;
    float* out_sgf = out;
    float* out_w   = out_sgf + (size_t)NB * NLQ * (NQS + NFS);
    float* out_e   = out_w   + (size_t)NB * NLQ * NLV;

    gemm_bt<<<dim3((NB * NLQ) / 64, NBN / 64), 256, 0, stream>>>(
        phr, W, bias, whb, NB * NLQ, NBN, NQS, 1);
    gemm_bt<<<dim3((NB * NLV) / 64, NBN / 64), 256, 0, stream>>>(
        vis, U, bias, uvb, NB * NLV, NBN, NFS, 0);
    attend<<<NB * 8, 512, 0, stream>>>(
        phr, vis, whb, uvb, wvec, out_sgf, out_w, out_e);
}

// Round 6
// 155.463 us; speedup vs baseline: 1.4225x; 1.4225x over previous
//
#include <hip/hip_runtime.h>

#define NB  32
#define NLQ 64
#define NLV 128
#define NQS 512
#define NFS 1024
#define NBN 512

typedef float  floatx4 __attribute__((ext_vector_type(4)));
typedef __bf16 bf16x8  __attribute__((ext_vector_type(8)));

__device__ __forceinline__ unsigned short f2bf(float f) {
    unsigned int u = __float_as_uint(f);
    u += 0x7fffu + ((u >> 16) & 1u);   // round-to-nearest-even
    return (unsigned short)(u >> 16);
}
// truncating pack: low half = hi16(lo), high half = hi16(hi) — one v_perm_b32
__device__ __forceinline__ unsigned int pktrunc(float lo, float hi) {
    return __builtin_amdgcn_perm(__float_as_uint(hi), __float_as_uint(lo), 0x07060302u);
}
__device__ __forceinline__ float blo(unsigned int u) {
    return __uint_as_float(u << 16);
}
__device__ __forceinline__ float bhi(unsigned int u) {
    return __uint_as_float(u & 0xffff0000u);
}

// ---------------- GEMM: C[M,N] = A[M,K] @ Bt[N,K]^T (+bias), bf16 MFMA ----
// 64x64 tile, 4 waves, K-tile 64, fp32->bf16 truncation pack on staging.
__device__ __forceinline__ void gemm_tile(
    unsigned short* As, unsigned short* Bs,     // [64*72] each
    const float* __restrict__ A,
    const float* __restrict__ Bt,
    const float* __restrict__ bias,
    unsigned short* __restrict__ C,
    int K, int bx, int by, int hasb)
{
    const int tid  = threadIdx.x;
    const int m0   = bx * 64;
    const int n0   = by * 64;
    const int wave = tid >> 6;
    const int lane = tid & 63;
    const int wm   = (wave >> 1) * 32;
    const int wn   = (wave & 1) * 32;
    const int srow = tid >> 2;          // 0..63 staging row
    const int sk   = (tid & 3) * 16;    // k offset: 0,16,32,48
    const int fm   = lane & 15;
    const int fko  = (lane >> 4) * 8;

    floatx4 acc00 = {0,0,0,0}, acc01 = {0,0,0,0};
    floatx4 acc10 = {0,0,0,0}, acc11 = {0,0,0,0};

    const float* ag = A  + (size_t)(m0 + srow) * K + sk;
    const float* bg = Bt + (size_t)(n0 + srow) * K + sk;

    for (int k0 = 0; k0 < K; k0 += 64) {
        float4 a[4], b[4];
        #pragma unroll
        for (int i = 0; i < 4; ++i) a[i] = *(const float4*)(ag + k0 + 4 * i);
        #pragma unroll
        for (int i = 0; i < 4; ++i) b[i] = *(const float4*)(bg + k0 + 4 * i);
        uint4 ap0 = { pktrunc(a[0].x, a[0].y), pktrunc(a[0].z, a[0].w),
                      pktrunc(a[1].x, a[1].y), pktrunc(a[1].z, a[1].w) };
        uint4 ap1 = { pktrunc(a[2].x, a[2].y), pktrunc(a[2].z, a[2].w),
                      pktrunc(a[3].x, a[3].y), pktrunc(a[3].z, a[3].w) };
        uint4 bp0 = { pktrunc(b[0].x, b[0].y), pktrunc(b[0].z, b[0].w),
                      pktrunc(b[1].x, b[1].y), pktrunc(b[1].z, b[1].w) };
        uint4 bp1 = { pktrunc(b[2].x, b[2].y), pktrunc(b[2].z, b[2].w),
                      pktrunc(b[3].x, b[3].y), pktrunc(b[3].z, b[3].w) };
        __syncthreads();
        *(uint4*)(As + srow * 72 + sk)     = ap0;
        *(uint4*)(As + srow * 72 + sk + 8) = ap1;
        *(uint4*)(Bs + srow * 72 + sk)     = bp0;
        *(uint4*)(Bs + srow * 72 + sk + 8) = bp1;
        __syncthreads();
        #pragma unroll
        for (int kk = 0; kk < 64; kk += 32) {
            bf16x8 fa0 = *(const bf16x8*)(As + (wm + fm) * 72 + kk + fko);
            bf16x8 fa1 = *(const bf16x8*)(As + (wm + 16 + fm) * 72 + kk + fko);
            bf16x8 fb0 = *(const bf16x8*)(Bs + (wn + fm) * 72 + kk + fko);
            bf16x8 fb1 = *(const bf16x8*)(Bs + (wn + 16 + fm) * 72 + kk + fko);
            acc00 = __builtin_amdgcn_mfma_f32_16x16x32_bf16(fa0, fb0, acc00, 0, 0, 0);
            acc01 = __builtin_amdgcn_mfma_f32_16x16x32_bf16(fa0, fb1, acc01, 0, 0, 0);
            acc10 = __builtin_amdgcn_mfma_f32_16x16x32_bf16(fa1, fb0, acc10, 0, 0, 0);
            acc11 = __builtin_amdgcn_mfma_f32_16x16x32_bf16(fa1, fb1, acc11, 0, 0, 0);
        }
    }

    // C/D layout: col = lane&15, row = (lane>>4)*4 + reg
    const int cr = (lane >> 4) * 4;
    const int cc = lane & 15;
    floatx4 accs[2][2] = {{acc00, acc01}, {acc10, acc11}};
    #pragma unroll
    for (int mt = 0; mt < 2; ++mt)
        #pragma unroll
        for (int nt = 0; nt < 2; ++nt)
            #pragma unroll
            for (int r = 0; r < 4; ++r) {
                int gm = m0 + wm + mt * 16 + cr + r;
                int gn = n0 + wn + nt * 16 + cc;
                float v = accs[mt][nt][r];
                if (hasb) v += bias[gn];
                C[(size_t)gm * NBN + gn] = f2bf(v);
            }
}

// blocks 0..255: Wh = phr@W^T + b (M=2048,K=512). blocks 256..767: Uv = vis@U^T (M=4096,K=1024)
__global__ __launch_bounds__(256) void gemm_both(
    const float* __restrict__ phr, const float* __restrict__ W,
    const float* __restrict__ bias,
    const float* __restrict__ vis, const float* __restrict__ U,
    unsigned short* __restrict__ whb, unsigned short* __restrict__ uvb)
{
    __shared__ __align__(16) unsigned short As[64 * 72];
    __shared__ __align__(16) unsigned short Bs[64 * 72];
    int blk = blockIdx.x;
    if (blk < 256) {
        gemm_tile(As, Bs, phr, W, bias, whb, NQS, blk >> 3, blk & 7, 1);
    } else {
        blk -= 256;
        gemm_tile(As, Bs, vis, U, bias, uvb, NFS, blk >> 3, blk & 7, 0);
    }
}

// ---------------- energies + softmax: one block per (b,q), 4 waves ----------
// blk = q*32 + b  (b in low bits -> same-b blocks share an XCD for uv locality)
__global__ __launch_bounds__(256) void energize(
    const unsigned short* __restrict__ whb,   // [2048,512] bf16
    const unsigned short* __restrict__ uv,    // [4096,512] bf16
    const float*          __restrict__ wvec,  // [512] fp32
    float* __restrict__ p_ws,                 // [2048,128] fp32
    float* __restrict__ out_w,                // [2048,128] fp32
    float* __restrict__ out_e)                // [2048,128] fp32
{
    const float LOG2E = 1.4426950408889634f;
    const float C     = 2.0f * LOG2E;
    const int blk  = blockIdx.x;
    const int q    = blk >> 5;
    const int b    = blk & 31;
    const int row  = b * NLQ + q;
    const int tid  = threadIdx.x;
    const int wave = tid >> 6;
    const int lane = tid & 63;

    __shared__ float e_s[128];

    // per-lane constants: 8 n's
    const int n0 = lane << 3;
    uint4 wv = *(const uint4*)(whb + (size_t)row * NBN + n0);
    float xc[8] = { blo(wv.x) * C, bhi(wv.x) * C, blo(wv.y) * C, bhi(wv.y) * C,
                    blo(wv.z) * C, bhi(wv.z) * C, blo(wv.w) * C, bhi(wv.w) * C };
    float4 w0 = *(const float4*)(wvec + n0);
    float4 w1 = *(const float4*)(wvec + n0 + 4);
    float nw2[8] = { 2.f*w0.x, 2.f*w0.y, 2.f*w0.z, 2.f*w0.w,
                     2.f*w1.x, 2.f*w1.y, 2.f*w1.z, 2.f*w1.w };
    float sumw = w0.x + w0.y + w0.z + w0.w + w1.x + w1.y + w1.z + w1.w;
    #pragma unroll
    for (int off = 32; off; off >>= 1) sumw += __shfl_xor(sumw, off);

    // tanh(x) = 1 - 2/(exp2(C*x)+1)  =>  e_v = sumw - sum_n 2*w_n/(exp2(C*x_n)+1)
    const unsigned short* uvb = uv + ((size_t)b * NLV + wave * 32) * NBN + n0;
    #pragma unroll 4
    for (int v = 0; v < 32; ++v) {
        uint4 u = *(const uint4*)(uvb + (size_t)v * NBN);
        float s = 0.f;
        auto term = [&](unsigned int uu, int j) {
            float y0 = __builtin_amdgcn_exp2f(fmaf(blo(uu), C, xc[j]));
            float y1 = __builtin_amdgcn_exp2f(fmaf(bhi(uu), C, xc[j + 1]));
            s = fmaf(nw2[j],     __builtin_amdgcn_rcpf(y0 + 1.f), s);
            s = fmaf(nw2[j + 1], __builtin_amdgcn_rcpf(y1 + 1.f), s);
        };
        term(u.x, 0); term(u.y, 2); term(u.z, 4); term(u.w, 6);
        #pragma unroll
        for (int off = 32; off; off >>= 1) s += __shfl_xor(s, off);
        if (lane == 0) e_s[wave * 32 + v] = sumw - s;
    }
    __syncthreads();

    if (wave == 0) {
        float e0 = e_s[lane];
        float e1 = e_s[lane + 64];
        float m = fmaxf(e0, e1);
        #pragma unroll
        for (int off = 32; off; off >>= 1) m = fmaxf(m, __shfl_xor(m, off));
        float x0 = __builtin_amdgcn_exp2f((e0 - m) * LOG2E);
        float x1 = __builtin_amdgcn_exp2f((e1 - m) * LOG2E);
        float ss = x0 + x1;
        #pragma unroll
        for (int off = 32; off; off >>= 1) ss += __shfl_xor(ss, off);
        float inv = __builtin_amdgcn_rcpf(ss);
        float p0 = x0 * inv, p1 = x1 * inv;
        size_t o = (size_t)row * NLV;
        p_ws[o + lane]       = p0;
        p_ws[o + lane + 64]  = p1;
        out_w[o + lane]      = p0;
        out_w[o + lane + 64] = p1;
        out_e[o + lane]      = e0;
        out_e[o + lane + 64] = e1;
    }
}

// ---------------- aligned + concat -----------------------------------------
// blk = ((qg*4 + fc) * 32) + b ; thread owns f = fc*256+tid for 8 q's.
__global__ __launch_bounds__(256) void aligned_k(
    const float* __restrict__ phr,    // [32,64,512]
    const float* __restrict__ vis,    // [32,128,1024]
    const float* __restrict__ p_ws,   // [2048,128]
    float* __restrict__ out_sgf)      // [32,64,1536]
{
    const int blk = blockIdx.x;
    const int b   = blk & 31;
    const int rest = blk >> 5;
    const int qg  = rest >> 2;        // 0..7
    const int fc  = rest & 3;         // 0..3
    const int tid = threadIdx.x;

    __shared__ float p_s[8][128];
    {
        const float* src = p_ws + (size_t)(b * NLQ + qg * 8) * NLV;
        ((float4*)&p_s[0][0])[tid] = ((const float4*)src)[tid];
    }
    __syncthreads();

    const int f = fc * 256 + tid;
    float acc[8] = {0.f, 0.f, 0.f, 0.f, 0.f, 0.f, 0.f, 0.f};
    const float* vcol = vis + (size_t)b * NLV * NFS + f;
    #pragma unroll 4
    for (int v = 0; v < NLV; ++v) {
        float x = vcol[(size_t)v * NFS];
        #pragma unroll
        for (int qq = 0; qq < 8; ++qq)
            acc[qq] = fmaf(p_s[qq][v], x, acc[qq]);
    }
    #pragma unroll
    for (int qq = 0; qq < 8; ++qq) {
        size_t row = (size_t)(b * NLQ + qg * 8 + qq);
        out_sgf[row * (NQS + NFS) + NQS + f] = acc[qq];
    }
    // concat: blocks with fc<2 copy phr columns [fc*256, fc*256+256)
    if (fc < 2) {
        const int col = fc * 256 + tid;
        #pragma unroll
        for (int qq = 0; qq < 8; ++qq) {
            size_t row = (size_t)(b * NLQ + qg * 8 + qq);
            out_sgf[row * (NQS + NFS) + col] = phr[row * NQS + col];
        }
    }
}

extern "C" void kernel_launch(void* const* d_in, const int* in_sizes, int n_in,
                              void* d_out, int out_size, void* d_ws, size_t ws_size,
                              hipStream_t stream) {
    const float* phr  = (const float*)d_in[0];
    const float* vis  = (const float*)d_in[1];
    const float* W    = (const float*)d_in[2];
    const float* U    = (const float*)d_in[3];
    const float* bias = (const float*)d_in[4];
    const float* wvec = (const float*)d_in[5];

    unsigned short* whb = (unsigned short*)d_ws;            // 2048x512 bf16 = 2 MB
    unsigned short* uvb = whb + (size_t)NB * NLQ * NBN;     // 4096x512 bf16 = 4 MB
    float* p_ws = (float*)(uvb + (size_t)NB * NLV * NBN);   // 2048x128 fp32 = 1 MB

    float* out     = (float*)d_out;
    float* out_sgf = out;
    float* out_w   = out_sgf + (size_t)NB * NLQ * (NQS + NFS);
    float* out_e   = out_w   + (size_t)NB * NLQ * NLV;

    gemm_both<<<768, 256, 0, stream>>>(phr, W, bias, vis, U, whb, uvb);
    energize<<<NB * NLQ, 256, 0, stream>>>(whb, uvb, wvec, p_ws, out_w, out_e);
    aligned_k<<<NB * 8 * 4, 256, 0, stream>>>(phr, vis, p_ws, out_sgf);
}